// Round 9
// baseline (249.773 us; speedup 1.0000x reference)
//
#include <hip/hip_runtime.h>
#include <hip/hip_cooperative_groups.h>
#include <cstddef>

namespace cg = cooperative_groups;

#define B_ 4
#define C_ 512
#define L_ 2048

typedef __attribute__((ext_vector_type(8))) short  short8;   // 8 bf16 (4 VGPRs)
typedef __attribute__((ext_vector_type(4))) float  f32x4;
typedef __attribute__((ext_vector_type(4))) unsigned short us4;

#define AS1 __attribute__((address_space(1)))
#define AS3 __attribute__((address_space(3)))

__device__ __forceinline__ float clip10(float v){ return fminf(fmaxf(v,-10.0f),10.0f); }

// round-to-nearest-even fp32 -> bf16 (finite inputs only; ours are clipped)
__device__ __forceinline__ unsigned short f2bf(float f){
  union { float f; unsigned u; } v; v.f = f;
  unsigned r = v.u + 0x7fffu + ((v.u >> 16) & 1u);
  return (unsigned short)(r >> 16);
}
// truncation-pack two fp32 -> bf16x2 in ONE v_perm_b32 (lo -> low half)
__device__ __forceinline__ unsigned pk_tr(float lo, float hi){
  return __builtin_amdgcn_perm(__float_as_uint(hi), __float_as_uint(lo), 0x07060302u);
}
__device__ __forceinline__ float bf2f(unsigned short u){
  return __uint_as_float(((unsigned)u)<<16);
}
// async 16B global -> LDS (direct-to-shared DMA)
__device__ __forceinline__ void gl16(const void* g, void* l){
  __builtin_amdgcn_global_load_lds((const AS1 unsigned*)g, (AS3 unsigned*)l, 16, 0, 0);
}
// explicit LDS-DMA drain: do NOT rely on compiler inserting vmcnt(0) at the
// barrier when the DMA issue is far from it.
__device__ __forceinline__ void drain_dma(){
  asm volatile("s_waitcnt vmcnt(0)" ::: "memory");
}
// assemble 4 packed-bf16 u32 words into one MFMA A/B fragment
__device__ __forceinline__ short8 mk8(unsigned a, unsigned b, unsigned c, unsigned d){
  union { unsigned u[4]; short8 s; } v;
  v.u[0]=a; v.u[1]=b; v.u[2]=c; v.u[3]=d;
  return v.s;
}

// ---------------------------------------------------------------------------
// Prep: blocks 0..4095 transpose x -> xT bf16; 4096..5119 convert W;
// block 5120 zeroes the groupnorm partial accumulators (re-poison-safe).
// ---------------------------------------------------------------------------
__global__ __launch_bounds__(256) void prep_k(
    const float* __restrict__ x, const float* __restrict__ Wq,
    const float* __restrict__ Wp, unsigned short* __restrict__ xT,
    unsigned short* __restrict__ Wqb, unsigned short* __restrict__ Wpb,
    float* __restrict__ part)
{
  const int blk = blockIdx.x;
  const int t = threadIdx.x;
  if (blk < 4096){
    __shared__ float tile[32][33];
    const int b = blk>>10, rem = blk&1023;
    const int c0 = (rem>>6)*32, l0 = (rem&63)*32;
    const int cr = t>>3, lc = (t&7)*4;
    const float4 v = *(const float4*)(x + ((size_t)b*C_ + c0+cr)*L_ + l0 + lc);
    tile[cr][lc]=v.x; tile[cr][lc+1]=v.y; tile[cr][lc+2]=v.z; tile[cr][lc+3]=v.w;
    __syncthreads();
    const int lr = t>>3, cc = (t&7)*4;
    const us4 o = { f2bf(tile[cc][lr]), f2bf(tile[cc+1][lr]),
                    f2bf(tile[cc+2][lr]), f2bf(tile[cc+3][lr]) };
    *(us4*)(xT + ((size_t)b*L_ + l0+lr)*C_ + c0 + cc) = o;
  } else if (blk < 5120){
    const int i = (blk-4096)*256 + t;       // float4 index
    const int NQ = 1536*512/4;
    const float* src; unsigned short* dst; int j;
    if (i < NQ){ src = Wq; dst = Wqb; j = i; }
    else       { src = Wp; dst = Wpb; j = i - NQ; }
    const float4 v = *(const float4*)(src + (size_t)j*4);
    const us4 o = { f2bf(v.x), f2bf(v.y), f2bf(v.z), f2bf(v.w) };
    *(us4*)(dst + (size_t)j*4) = o;
  } else {
    part[t] = 0.f;                          // 4 batches x 32 groups x {sum,sq}
  }
}

// ---------------------------------------------------------------------------
// bf16 MFMA QKV GEMM (LDS-DMA), 128x128 tile, BK=64, K=512. (round-2 verified)
// LDS chunks XOR-swizzled: physical chunk = logical ^ (row&7).
// +bias, clip; q scaled by 0.125*log2e; q/k bf16 [b][l][512];
// v bf16 [b][512][l] with l J-PERMUTED inside each 64-block
// (p = (u&3)|(u5<<2)|(u2<<3)|(u3<<4)|(u4<<5)) so the attention
// PV A-fragment assembles in-register with no LDS P bounce.
// ---------------------------------------------------------------------------
__global__ __launch_bounds__(256) void qkv_gemm(
    const unsigned short* __restrict__ Wb, const unsigned short* __restrict__ Bin,
    const float* __restrict__ bias,
    unsigned short* __restrict__ qT, unsigned short* __restrict__ kT,
    unsigned short* __restrict__ vN)
{
  __shared__ unsigned short SA[128*64];   // [m][k'] bf16, 16KB
  __shared__ unsigned short SB[128*64];   // [n][k'] bf16, 16KB
  const int t = threadIdx.x;
  const int b = blockIdx.z;
  const int mb = blockIdx.y, n0 = blockIdx.x*128, m0 = mb*128;
  const int lane = t&63, w = t>>6, wm = w>>1, wn = w&1;
  const int n = lane&15, q4 = lane>>4;
  const bool VSWAP = (mb>=8);

  f32x4 acc[4][4];
#pragma unroll
  for (int i=0;i<4;i++)
#pragma unroll
    for (int j=0;j<4;j++) acc[i][j] = (f32x4){0.f,0.f,0.f,0.f};

  const unsigned short* Arow = Wb + (size_t)m0*512;
  const unsigned short* Brow = Bin + ((size_t)b*L_ + n0)*512;

  for (int kt=0; kt<8; kt++){
    const int k0 = kt*64;
    __syncthreads();                     // prev-iter fragment reads done
#pragma unroll
    for (int i=0;i<4;i++){
      const int ch = t + 256*i;          // 0..1023 : row=ch>>3, phys chunk=ch&7
      const int row = ch>>3, lc = (ch&7) ^ (row&7);
      gl16(Arow + (size_t)row*512 + k0 + lc*8, &SA[ch*8]);
      gl16(Brow + (size_t)row*512 + k0 + lc*8, &SB[ch*8]);
    }
    drain_dma();
    __syncthreads();                     // all DMA landed
#pragma unroll
    for (int kk=0;kk<2;kk++){
      short8 aF[4], bF[4];
      const int pc = ((kk*4+q4) ^ (n&7))*8;
#pragma unroll
      for (int mt=0;mt<4;mt++) aF[mt] = *(const short8*)&SA[(wm*64+mt*16+n)*64 + pc];
#pragma unroll
      for (int nt=0;nt<4;nt++) bF[nt] = *(const short8*)&SB[(wn*64+nt*16+n)*64 + pc];
      if (VSWAP){
#pragma unroll
        for (int mt=0;mt<4;mt++)
#pragma unroll
          for (int nt=0;nt<4;nt++)
            acc[mt][nt] = __builtin_amdgcn_mfma_f32_16x16x32_bf16(bF[nt], aF[mt], acc[mt][nt], 0,0,0);
      } else {
#pragma unroll
        for (int mt=0;mt<4;mt++)
#pragma unroll
          for (int nt=0;nt<4;nt++)
            acc[mt][nt] = __builtin_amdgcn_mfma_f32_16x16x32_bf16(aF[mt], bF[nt], acc[mt][nt], 0,0,0);
      }
    }
  }

  const float QS = 0.180336880f;   // 0.125 * log2(e), folded into q
  if (VSWAP){
    // D^T: acc[mt][nt][r] = value at logical l = n0+wn*64+nt*16+q4*4+r,
    //                       c = m0+wm*64+mt*16+n  (channel 1024..1535)
    // store at J-PERMUTED l within the 64-block: u=nt*16+q4*4+r ->
    //   p = r + (nt>>1)*4 + (q4&1)*8 + (q4>>1)*16 + (nt&1)*32
#pragma unroll
    for (int mt=0;mt<4;mt++){
      const int o = m0 + wm*64 + mt*16 + n;
      const float bv = bias[o];
#pragma unroll
      for (int nt=0;nt<4;nt++){
        const int p = ((nt>>1)<<2) | ((q4&1)<<3) | ((q4>>1)<<4) | ((nt&1)<<5);
        const int l = n0 + wn*64 + p;
        const float r0=clip10(acc[mt][nt][0]+bv), r1=clip10(acc[mt][nt][1]+bv),
                    r2=clip10(acc[mt][nt][2]+bv), r3=clip10(acc[mt][nt][3]+bv);
        const us4 ov = { f2bf(r0), f2bf(r1), f2bf(r2), f2bf(r3) };
        *(us4*)&vN[((size_t)b*512 + (o-1024))*L_ + l] = ov;   // 8B store along l
      }
    }
    return;
  }
  // ---- normal epilogue: C row = m (quad*4+reg), col = n (lane&15)
#pragma unroll
  for (int mt=0;mt<4;mt++){
    const int obase = m0 + wm*64 + mt*16 + q4*4;
    const float b0=bias[obase], b1=bias[obase+1], b2=bias[obase+2], b3=bias[obase+3];
#pragma unroll
    for (int nt=0;nt<4;nt++){
      const int l = n0 + wn*64 + nt*16 + n;
      float r0=clip10(acc[mt][nt][0]+b0), r1=clip10(acc[mt][nt][1]+b1),
            r2=clip10(acc[mt][nt][2]+b2), r3=clip10(acc[mt][nt][3]+b3);
      const int typ = mb>>2;                     // 0=q 1=k (v handled above)
      const int oin = obase - typ*512;
      if (typ==0){ r0*=QS; r1*=QS; r2*=QS; r3*=QS; }
      unsigned short* dst = (typ==0) ? qT : kT;
      const us4 o = { f2bf(r0), f2bf(r1), f2bf(r2), f2bf(r3) };
      *(us4*)&dst[((size_t)b*L_ + l)*512 + oin] = o;   // [l][c], 8B store
    }
  }
}

// ---------------------------------------------------------------------------
// Fused proj GEMM + GroupNorm (cooperative, 256 blocks = 1/CU co-resident).
// Phase 1: proj GEMM (same verified 128x128 structure); epilogue keeps
//   y = proj + bias + x IN REGISTERS (overwrites acc), wave-reduces per-group
//   sum/sumsq, atomicAdd into part[] (zeroed by prep_k).
// Phase 2: grid.sync(); each thread normalizes its own register tile with the
//   now-complete stats and writes out directly. Deletes the y buffer
//   (33.6MB round-trip) and the gn_apply kernel+launch. Arithmetic identical
//   to the previous two-kernel path.
// ---------------------------------------------------------------------------
__global__ __launch_bounds__(256) void proj_gn(
    const unsigned short* __restrict__ Wb, const unsigned short* __restrict__ Bin,
    const float* __restrict__ bias, const float* __restrict__ xres,
    float* __restrict__ part, const float* __restrict__ gamma,
    const float* __restrict__ beta, float* __restrict__ out)
{
  __shared__ unsigned short SA[128*64];   // 16KB
  __shared__ unsigned short SB[128*64];   // 16KB
  const int t = threadIdx.x;
  const int b = blockIdx.z;
  const int mb = blockIdx.y, n0 = blockIdx.x*128, m0 = mb*128;
  const int lane = t&63, w = t>>6, wm = w>>1, wn = w&1;
  const int n = lane&15, q4 = lane>>4;

  f32x4 acc[4][4];
#pragma unroll
  for (int i=0;i<4;i++)
#pragma unroll
    for (int j=0;j<4;j++) acc[i][j] = (f32x4){0.f,0.f,0.f,0.f};

  const unsigned short* Arow = Wb + (size_t)m0*512;
  const unsigned short* Brow = Bin + ((size_t)b*L_ + n0)*512;

  for (int kt=0; kt<8; kt++){
    const int k0 = kt*64;
    __syncthreads();
#pragma unroll
    for (int i=0;i<4;i++){
      const int ch = t + 256*i;
      const int row = ch>>3, lc = (ch&7) ^ (row&7);
      gl16(Arow + (size_t)row*512 + k0 + lc*8, &SA[ch*8]);
      gl16(Brow + (size_t)row*512 + k0 + lc*8, &SB[ch*8]);
    }
    drain_dma();
    __syncthreads();
#pragma unroll
    for (int kk=0;kk<2;kk++){
      short8 aF[4], bF[4];
      const int pc = ((kk*4+q4) ^ (n&7))*8;
#pragma unroll
      for (int mt=0;mt<4;mt++) aF[mt] = *(const short8*)&SA[(wm*64+mt*16+n)*64 + pc];
#pragma unroll
      for (int nt=0;nt<4;nt++) bF[nt] = *(const short8*)&SB[(wn*64+nt*16+n)*64 + pc];
#pragma unroll
      for (int mt=0;mt<4;mt++)
#pragma unroll
        for (int nt=0;nt<4;nt++)
          acc[mt][nt] = __builtin_amdgcn_mfma_f32_16x16x32_bf16(aF[mt], bF[nt], acc[mt][nt], 0,0,0);
    }
  }

  // ---- phase 1 epilogue: y = acc + bias + x (kept in acc); group stats
#pragma unroll
  for (int mt=0;mt<4;mt++){
    const int obase = m0 + wm*64 + mt*16 + q4*4;
    const float b0=bias[obase], b1=bias[obase+1], b2=bias[obase+2], b3=bias[obase+3];
    float gs=0.f, gq=0.f;
#pragma unroll
    for (int nt=0;nt<4;nt++){
      const int l = n0 + wn*64 + nt*16 + n;
      const float* xp = xres + ((size_t)b*512 + obase)*L_ + l;
      const float y0=acc[mt][nt][0]+b0+xp[0],
                  y1=acc[mt][nt][1]+b1+xp[(size_t)L_],
                  y2=acc[mt][nt][2]+b2+xp[(size_t)2*L_],
                  y3=acc[mt][nt][3]+b3+xp[(size_t)3*L_];
      acc[mt][nt][0]=y0; acc[mt][nt][1]=y1; acc[mt][nt][2]=y2; acc[mt][nt][3]=y3;
      gs += (y0+y1)+(y2+y3);
      gq += (y0*y0+y1*y1)+(y2*y2+y3*y3);
    }
    // whole wave belongs to one 16-channel group for this mt
#pragma unroll
    for (int off=1; off<64; off<<=1){
      gs += __shfl_xor(gs, off);
      gq += __shfl_xor(gq, off);
    }
    if (lane==0){
      const int g = mb*8 + wm*4 + mt;
      atomicAdd(&part[(b*32+g)*2+0], gs);
      atomicAdd(&part[(b*32+g)*2+1], gq);
    }
  }

  __threadfence();
  cg::this_grid().sync();          // all 256 blocks' stats complete

  // ---- phase 2: normalize register tile, write out directly
#pragma unroll
  for (int mt=0;mt<4;mt++){
    const int g = mb*8 + wm*4 + mt;
    const float sum = part[(b*32+g)*2+0];
    const float sq  = part[(b*32+g)*2+1];
    const float mu = sum*(1.0f/32768.0f);
    const float rs = rsqrtf(sq*(1.0f/32768.0f) - mu*mu + 1e-5f);
    const int obase = m0 + wm*64 + mt*16 + q4*4;
    const float ga0=gamma[obase]*rs,   ga1=gamma[obase+1]*rs,
                ga2=gamma[obase+2]*rs, ga3=gamma[obase+3]*rs;
    const float be0=beta[obase]   - mu*ga0, be1=beta[obase+1] - mu*ga1,
                be2=beta[obase+2] - mu*ga2, be3=beta[obase+3] - mu*ga3;
#pragma unroll
    for (int nt=0;nt<4;nt++){
      const int l = n0 + wn*64 + nt*16 + n;
      float* dst = out + ((size_t)b*512 + obase)*L_ + l;
      dst[0]            = acc[mt][nt][0]*ga0 + be0;
      dst[(size_t)L_]   = acc[mt][nt][1]*ga1 + be1;
      dst[(size_t)2*L_] = acc[mt][nt][2]*ga2 + be2;
      dst[(size_t)3*L_] = acc[mt][nt][3]*ga3 + be3;
    }
  }
}

// ---------------------------------------------------------------------------
// MFMA attention v13 (round-6 verified best: 43.8us, FETCH 12.3MB):
// full-j single-pass, combine-free, i-tile 128, 8 waves, dbuf K/V staging
// with explicit drain, in-register P fragments (j-permuted vN), XCD-clustered
// block decode. (v14's KBLK=128 was neutral — reverted.)
// ---------------------------------------------------------------------------
#define OPX 68  // epilogue bounce pitch

__global__ __launch_bounds__(512,4) void attn_v13(
    const unsigned short* __restrict__ qT, const unsigned short* __restrict__ kT,
    const unsigned short* __restrict__ vN,
    unsigned short* __restrict__ attnT)
{
  __shared__ unsigned short smem[16384];   // 32KB: buf b: K @ b*8192, V @ b*8192+4096
  const int t  = threadIdx.x;
  // ---- XCD-clustered decode
  const int id  = blockIdx.x;
  const int xcd = id & 7, s = id >> 3;
  const int pr  = xcd*4 + (s & 3);         // pair 0..31
  const int i0  = (s >> 2) * 128;          // i-tile 0..15
  const int h   = pr & 7, b = pr >> 3;
  const int lane = t&63, w = t>>6, n = lane&15, q4 = lane>>4;

  const unsigned short* kb0 = kT + (size_t)b*L_*512 + h*64;
  const unsigned short* vb  = vN + ((size_t)b*512 + h*64)*L_;

  // ---- Q B-fragments for this wave's 16 i-rows (col i = n)
  short8 qf[2];
#pragma unroll
  for (int kk=0; kk<2; kk++)
    qf[kk] = *(const short8*)(qT + ((size_t)b*L_ + i0 + w*16 + n)*512
                                 + h*64 + kk*32 + q4*8);

  // ---- all-ones bf16 B-fragment for the denominator MFMA
  short8 ones;
#pragma unroll
  for (int i=0;i<8;i++) ones[i] = (short)0x3F80;

  f32x4 oacc[4];
  f32x4 oden = (f32x4){0.f,0.f,0.f,0.f};
#pragma unroll
  for (int dt=0;dt<4;dt++) oacc[dt]=(f32x4){0.f,0.f,0.f,0.f};

  const float LIM = 14.4269504089f;          // 10*log2(e)

  // ---- prologue: stage tile 0 into buf0 (512 threads = 512 chunks each)
  {
    const int ch = t, row = ch>>3, lc = (ch&7)^(row&7);
    gl16(kb0 + (size_t)row*512 + lc*8, &smem[ch*8]);
    gl16(vb  + (size_t)row*L_ + lc*8,  &smem[4096 + ch*8]);
  }
  drain_dma();
  __syncthreads();                           // tile 0 landed (all waves)

  for (int j0=0; j0<L_; j0+=64){
    const int cur = (j0>>6)&1;
    const unsigned short* sk = &smem[cur*8192];
    const unsigned short* sv = &smem[cur*8192 + 4096];

    // ---- issue next tile's DMA into the other buffer (flight hides under
    //      this tile's MFMAs; drained explicitly before the loop barrier)
    if (j0+64 < L_){
      const int nb = cur^1;
      const int ch = t, row = ch>>3, lc = (ch&7)^(row&7);
      gl16(kb0 + (size_t)(j0+64+row)*512 + lc*8, &smem[nb*8192 + ch*8]);
      gl16(vb  + (size_t)row*L_ + j0+64 + lc*8,  &smem[nb*8192+4096 + ch*8]);
    }

    // ---- S^T = K*Q^T : D[j][i]; lane col = i (n), rows j = q4*4+r (+jt*16)
    f32x4 sacc[4];   // [jt]
#pragma unroll
    for (int jt=0;jt<4;jt++) sacc[jt]=(f32x4){0.f,0.f,0.f,0.f};
#pragma unroll
    for (int kk=0;kk<2;kk++){
      const int pc = ((kk*4+q4) ^ (n&7))*8;
      short8 aK[4];
#pragma unroll
      for (int jt=0;jt<4;jt++) aK[jt] = *(const short8*)&sk[(jt*16+n)*64 + pc];
#pragma unroll
      for (int jt=0;jt<4;jt++)
        sacc[jt] = __builtin_amdgcn_mfma_f32_16x16x32_bf16(aK[jt], qf[kk], sacc[jt], 0,0,0);
    }

    // ---- p = exp2(clamp(s)); trunc-pack pairs -> u32 words, kept in regs
    unsigned pw[4][2];
#pragma unroll
    for (int jt=0;jt<4;jt++){
      const float e0 = __builtin_amdgcn_exp2f(__builtin_amdgcn_fmed3f(sacc[jt][0],-LIM,LIM));
      const float e1 = __builtin_amdgcn_exp2f(__builtin_amdgcn_fmed3f(sacc[jt][1],-LIM,LIM));
      const float e2 = __builtin_amdgcn_exp2f(__builtin_amdgcn_fmed3f(sacc[jt][2],-LIM,LIM));
      const float e3 = __builtin_amdgcn_exp2f(__builtin_amdgcn_fmed3f(sacc[jt][3],-LIM,LIM));
      pw[jt][0] = pk_tr(e0,e1);
      pw[jt][1] = pk_tr(e2,e3);
    }

    // ---- O += P*V^T ; den += P*1. A-fragment built IN-REGISTER:
    // pA[kk] = {pw[kk][0], pw[kk][1], pw[kk+2][0], pw[kk+2][1]} holds
    // j = 16kk+4*q4+{0..3} and +32, matching the j-permuted s_v positions.
#pragma unroll
    for (int kk=0;kk<2;kk++){
      const int pcv = ((kk*4+q4) ^ (n&7))*8;
      short8 bV[4];
#pragma unroll
      for (int dt=0;dt<4;dt++) bV[dt] = *(const short8*)&sv[(dt*16+n)*64 + pcv];
      const short8 pA = mk8(pw[kk][0], pw[kk][1], pw[kk+2][0], pw[kk+2][1]);
#pragma unroll
      for (int dt=0;dt<4;dt++)
        oacc[dt] = __builtin_amdgcn_mfma_f32_16x16x32_bf16(pA, bV[dt], oacc[dt], 0,0,0);
      oden = __builtin_amdgcn_mfma_f32_16x16x32_bf16(pA, ones, oden, 0,0,0);
    }
    drain_dma();       // prefetch landed (explicit — do not trust barrier)
    __syncthreads();   // all waves done reading cur + all DMA drained
  }

  // ---- softmax divide in-register: oden[r] = den for row i = q4*4+r
  float inv[4];
#pragma unroll
  for (int r=0;r<4;r++) inv[r] = 1.0f/oden[r];

  // ---- epilogue: bounce O through the dead staging LDS (wave-private rows;
  // safe: last loop barrier already passed), then fully-coalesced 8B stores.
  unsigned short* sb = smem;   // 128 rows x OPX = 8704 us, fits in 16384
#pragma unroll
  for (int dt=0;dt<4;dt++)
#pragma unroll
    for (int r=0;r<4;r++)
      sb[(w*16 + q4*4 + r)*OPX + dt*16 + n] = f2bf(oacc[dt][r]*inv[r]);
#pragma unroll
  for (int it=0; it<4; it++){
    const int chunk = it*64 + lane;          // 256 us4 chunks for this wave
    const int row = chunk>>4, c4 = (chunk&15)*4;
    const us4 ov = *(const us4*)&sb[(w*16 + row)*OPX + c4];
    *(us4*)&attnT[((size_t)b*L_ + i0 + w*16 + row)*512 + h*64 + c4] = ov;
  }
}

// ---------------------------------------------------------------------------
extern "C" void kernel_launch(void* const* d_in, const int* in_sizes, int n_in,
                              void* d_out, int out_size, void* d_ws, size_t ws_size,
                              hipStream_t stream)
{
  (void)in_sizes; (void)n_in; (void)out_size; (void)ws_size;
  const float* x     = (const float*)d_in[0];
  const float* Wqkv  = (const float*)d_in[1];
  const float* bqkv  = (const float*)d_in[2];
  const float* Wproj = (const float*)d_in[3];
  const float* bproj = (const float*)d_in[4];
  const float* gamma = (const float*)d_in[5];
  const float* beta  = (const float*)d_in[6];
  float* out = (float*)d_out;
  char* ws = (char*)d_ws;

  const size_t MB = 1024*1024;
  unsigned short* qT    = (unsigned short*)(ws);            //  8 MB [b][l][512] (pre-scaled)
  unsigned short* kT    = (unsigned short*)(ws +  8*MB);    //  8 MB [b][l][512]
  unsigned short* vN    = (unsigned short*)(ws + 16*MB);    //  8 MB [b][512][l] (j-permuted)
  unsigned short* attnT = (unsigned short*)(ws + 24*MB);    //  8 MB [b][l][512]
  unsigned short* xT    = (unsigned short*)(ws + 32*MB);    //  8 MB; dead after QKV gemm
  unsigned short* Wqb   = (unsigned short*)(ws + 42*MB);    // 1.5 MB
  unsigned short* Wpb   = (unsigned short*)(ws + 44*MB);    // 0.5 MB
  float*          part  = (float*)        (ws + 61*MB);     // 1 KB (256 floats)

  prep_k  <<<dim3(5121),   256,0,stream>>>(x, Wqkv, Wproj, xT, Wqb, Wpb, part);
  qkv_gemm<<<dim3(16,12,4),256,0,stream>>>(Wqb, xT, bqkv, qT, kT, vN);
  attn_v13<<<dim3(512),    512,0,stream>>>(qT, kT, vN, attnT);

  // fused proj+GN: cooperative (256 blocks = 1/CU, co-resident for grid sync)
  {
    const unsigned short* Wpb_c = Wpb;
    const unsigned short* attnT_c = attnT;
    void* args[] = { (void*)&Wpb_c, (void*)&attnT_c, (void*)&bproj, (void*)&x,
                     (void*)&part, (void*)&gamma, (void*)&beta, (void*)&out };
    hipLaunchCooperativeKernel((const void*)proj_gn, dim3(16,4,4), dim3(256),
                               args, 0, stream);
  }
}

// Round 10
// 175.532 us; speedup vs baseline: 1.4230x; 1.4230x over previous
//
#include <hip/hip_runtime.h>
#include <cstddef>

#define B_ 4
#define C_ 512
#define L_ 2048

typedef __attribute__((ext_vector_type(8))) short  short8;   // 8 bf16 (4 VGPRs)
typedef __attribute__((ext_vector_type(4))) float  f32x4;
typedef __attribute__((ext_vector_type(4))) unsigned short us4;

#define AS1 __attribute__((address_space(1)))
#define AS3 __attribute__((address_space(3)))

__device__ __forceinline__ float clip10(float v){ return fminf(fmaxf(v,-10.0f),10.0f); }

// round-to-nearest-even fp32 -> bf16 (finite inputs only; ours are clipped)
__device__ __forceinline__ unsigned short f2bf(float f){
  union { float f; unsigned u; } v; v.f = f;
  unsigned r = v.u + 0x7fffu + ((v.u >> 16) & 1u);
  return (unsigned short)(r >> 16);
}
// truncation-pack two fp32 -> bf16x2 in ONE v_perm_b32 (lo -> low half)
__device__ __forceinline__ unsigned pk_tr(float lo, float hi){
  return __builtin_amdgcn_perm(__float_as_uint(hi), __float_as_uint(lo), 0x07060302u);
}
__device__ __forceinline__ float bf2f(unsigned short u){
  return __uint_as_float(((unsigned)u)<<16);
}
// async 16B global -> LDS (direct-to-shared DMA)
__device__ __forceinline__ void gl16(const void* g, void* l){
  __builtin_amdgcn_global_load_lds((const AS1 unsigned*)g, (AS3 unsigned*)l, 16, 0, 0);
}
// explicit LDS-DMA drain: do NOT rely on compiler inserting vmcnt(0) at the
// barrier when the DMA issue is far from it.
__device__ __forceinline__ void drain_dma(){
  asm volatile("s_waitcnt vmcnt(0)" ::: "memory");
}
// assemble 4 packed-bf16 u32 words into one MFMA A/B fragment
__device__ __forceinline__ short8 mk8(unsigned a, unsigned b, unsigned c, unsigned d){
  union { unsigned u[4]; short8 s; } v;
  v.u[0]=a; v.u[1]=b; v.u[2]=c; v.u[3]=d;
  return v.s;
}

// ---------------------------------------------------------------------------
// Prep: blocks 0..4095 transpose x -> xT bf16; 4096..5119 convert W;
// block 5120 zeroes the groupnorm partial accumulators (re-poison-safe).
// ---------------------------------------------------------------------------
__global__ __launch_bounds__(256) void prep_k(
    const float* __restrict__ x, const float* __restrict__ Wq,
    const float* __restrict__ Wp, unsigned short* __restrict__ xT,
    unsigned short* __restrict__ Wqb, unsigned short* __restrict__ Wpb,
    float* __restrict__ part)
{
  const int blk = blockIdx.x;
  const int t = threadIdx.x;
  if (blk < 4096){
    __shared__ float tile[32][33];
    const int b = blk>>10, rem = blk&1023;
    const int c0 = (rem>>6)*32, l0 = (rem&63)*32;
    const int cr = t>>3, lc = (t&7)*4;
    const float4 v = *(const float4*)(x + ((size_t)b*C_ + c0+cr)*L_ + l0 + lc);
    tile[cr][lc]=v.x; tile[cr][lc+1]=v.y; tile[cr][lc+2]=v.z; tile[cr][lc+3]=v.w;
    __syncthreads();
    const int lr = t>>3, cc = (t&7)*4;
    const us4 o = { f2bf(tile[cc][lr]), f2bf(tile[cc+1][lr]),
                    f2bf(tile[cc+2][lr]), f2bf(tile[cc+3][lr]) };
    *(us4*)(xT + ((size_t)b*L_ + l0+lr)*C_ + c0 + cc) = o;
  } else if (blk < 5120){
    const int i = (blk-4096)*256 + t;       // float4 index
    const int NQ = 1536*512/4;
    const float* src; unsigned short* dst; int j;
    if (i < NQ){ src = Wq; dst = Wqb; j = i; }
    else       { src = Wp; dst = Wpb; j = i - NQ; }
    const float4 v = *(const float4*)(src + (size_t)j*4);
    const us4 o = { f2bf(v.x), f2bf(v.y), f2bf(v.z), f2bf(v.w) };
    *(us4*)(dst + (size_t)j*4) = o;
  } else {
    part[t] = 0.f;                          // 4 batches x 32 groups x {sum,sq}
  }
}

// ---------------------------------------------------------------------------
// bf16 MFMA GEMM (LDS-DMA), 128x128 tile, BK=64, K=512. (round-2 verified)
// LDS chunks XOR-swizzled: physical chunk = logical ^ (row&7).
// MODE 0 (QKV): +bias, clip; q scaled by 0.125*log2e; q/k bf16 [b][l][512];
//               v bf16 [b][512][l] with l J-PERMUTED inside each 64-block
//               so the attention PV A-fragment assembles in-register.
// MODE 1 (proj): SWAPPED operands (D^T, same verified mapping as VSWAP, no
//               permutation): lane owns 4 CONSECUTIVE l of one channel ->
//               x residual = one float4 load, y = one us4 bf16 store (8B,
//               coalesced, half traffic). Stats in fp32 BEFORE rounding;
//               per-group sum/sumsq wave-reduced, atomicAdd into part[].
// ---------------------------------------------------------------------------
template<int MODE>
__global__ __launch_bounds__(256) void mfma_gemm(
    const unsigned short* __restrict__ Wb, const unsigned short* __restrict__ Bin,
    const float* __restrict__ bias, const float* __restrict__ xres,
    unsigned short* __restrict__ qT, unsigned short* __restrict__ kT,
    unsigned short* __restrict__ vN,      // MODE1: yb bf16 [b][512][l]
    float* __restrict__ part)
{
  __shared__ unsigned short SA[128*64];   // [m][k'] bf16, 16KB
  __shared__ unsigned short SB[128*64];   // [n][k'] bf16, 16KB
  const int t = threadIdx.x;
  const int b = blockIdx.z;
  const int mb = blockIdx.y, n0 = blockIdx.x*128, m0 = mb*128;
  const int lane = t&63, w = t>>6, wm = w>>1, wn = w&1;
  const int n = lane&15, q4 = lane>>4;
  const bool SWAP = (MODE==1) || (MODE==0 && mb>=8);

  f32x4 acc[4][4];
#pragma unroll
  for (int i=0;i<4;i++)
#pragma unroll
    for (int j=0;j<4;j++) acc[i][j] = (f32x4){0.f,0.f,0.f,0.f};

  const unsigned short* Arow = Wb + (size_t)m0*512;
  const unsigned short* Brow = Bin + ((size_t)b*L_ + n0)*512;

  for (int kt=0; kt<8; kt++){
    const int k0 = kt*64;
    __syncthreads();                     // prev-iter fragment reads done
#pragma unroll
    for (int i=0;i<4;i++){
      const int ch = t + 256*i;          // 0..1023 : row=ch>>3, phys chunk=ch&7
      const int row = ch>>3, lc = (ch&7) ^ (row&7);
      gl16(Arow + (size_t)row*512 + k0 + lc*8, &SA[ch*8]);
      gl16(Brow + (size_t)row*512 + k0 + lc*8, &SB[ch*8]);
    }
    drain_dma();
    __syncthreads();                     // all DMA landed
#pragma unroll
    for (int kk=0;kk<2;kk++){
      short8 aF[4], bF[4];
      const int pc = ((kk*4+q4) ^ (n&7))*8;
#pragma unroll
      for (int mt=0;mt<4;mt++) aF[mt] = *(const short8*)&SA[(wm*64+mt*16+n)*64 + pc];
#pragma unroll
      for (int nt=0;nt<4;nt++) bF[nt] = *(const short8*)&SB[(wn*64+nt*16+n)*64 + pc];
      if (SWAP){
#pragma unroll
        for (int mt=0;mt<4;mt++)
#pragma unroll
          for (int nt=0;nt<4;nt++)
            acc[mt][nt] = __builtin_amdgcn_mfma_f32_16x16x32_bf16(bF[nt], aF[mt], acc[mt][nt], 0,0,0);
      } else {
#pragma unroll
        for (int mt=0;mt<4;mt++)
#pragma unroll
          for (int nt=0;nt<4;nt++)
            acc[mt][nt] = __builtin_amdgcn_mfma_f32_16x16x32_bf16(aF[mt], bF[nt], acc[mt][nt], 0,0,0);
      }
    }
  }

  const float QS = 0.180336880f;   // 0.125 * log2(e), folded into q
  if (MODE==0 && SWAP){
    // D^T: acc[mt][nt][r] = (l = n0+wn*64+nt*16+q4*4+r, c = m0+wm*64+mt*16+n)
    // store at J-PERMUTED l within the 64-block: u=nt*16+q4*4+r ->
    //   p = r + (nt>>1)*4 + (q4&1)*8 + (q4>>1)*16 + (nt&1)*32
#pragma unroll
    for (int mt=0;mt<4;mt++){
      const int o = m0 + wm*64 + mt*16 + n;
      const float bv = bias[o];
#pragma unroll
      for (int nt=0;nt<4;nt++){
        const int p = ((nt>>1)<<2) | ((q4&1)<<3) | ((q4>>1)<<4) | ((nt&1)<<5);
        const int l = n0 + wn*64 + p;
        const float r0=clip10(acc[mt][nt][0]+bv), r1=clip10(acc[mt][nt][1]+bv),
                    r2=clip10(acc[mt][nt][2]+bv), r3=clip10(acc[mt][nt][3]+bv);
        const us4 ov = { f2bf(r0), f2bf(r1), f2bf(r2), f2bf(r3) };
        *(us4*)&vN[((size_t)b*512 + (o-1024))*L_ + l] = ov;   // 8B store along l
      }
    }
    return;
  }
  if (MODE==1){
    // D^T, NO permutation: acc[mt][nt][r] = y at (c = m0+wm*64+mt*16+n,
    // l = n0+wn*64+nt*16+q4*4+r). One float4 x-load + one us4 y-store per nt.
#pragma unroll
    for (int mt=0;mt<4;mt++){
      const int o = m0 + wm*64 + mt*16 + n;
      const float bv = bias[o];
      float gs=0.f, gq=0.f;
#pragma unroll
      for (int nt=0;nt<4;nt++){
        const int l = n0 + wn*64 + nt*16 + q4*4;
        const float4 xv = *(const float4*)(xres + ((size_t)b*512 + o)*L_ + l);
        const float y0=acc[mt][nt][0]+bv+xv.x, y1=acc[mt][nt][1]+bv+xv.y,
                    y2=acc[mt][nt][2]+bv+xv.z, y3=acc[mt][nt][3]+bv+xv.w;
        gs += (y0+y1)+(y2+y3);
        gq += (y0*y0+y1*y1)+(y2*y2+y3*y3);
        const us4 ov = { f2bf(y0), f2bf(y1), f2bf(y2), f2bf(y3) };
        *(us4*)&vN[((size_t)b*512 + o)*L_ + l] = ov;          // yb, 8B along l
      }
      // wave covers exactly one 16-channel group for this mt
#pragma unroll
      for (int off=1; off<64; off<<=1){
        gs += __shfl_xor(gs, off);
        gq += __shfl_xor(gq, off);
      }
      if (lane==0){
        const int g = mb*8 + wm*4 + mt;
        atomicAdd(&part[(b*32+g)*2+0], gs);
        atomicAdd(&part[(b*32+g)*2+1], gq);
      }
    }
    return;
  }
  // ---- MODE0 q/k epilogue: C row = m (quad*4+reg), col = n (lane&15)
#pragma unroll
  for (int mt=0;mt<4;mt++){
    const int obase = m0 + wm*64 + mt*16 + q4*4;
    const float b0=bias[obase], b1=bias[obase+1], b2=bias[obase+2], b3=bias[obase+3];
#pragma unroll
    for (int nt=0;nt<4;nt++){
      const int l = n0 + wn*64 + nt*16 + n;
      float r0=clip10(acc[mt][nt][0]+b0), r1=clip10(acc[mt][nt][1]+b1),
            r2=clip10(acc[mt][nt][2]+b2), r3=clip10(acc[mt][nt][3]+b3);
      const int typ = mb>>2;                     // 0=q 1=k (v handled above)
      const int oin = obase - typ*512;
      if (typ==0){ r0*=QS; r1*=QS; r2*=QS; r3*=QS; }
      unsigned short* dst = (typ==0) ? qT : kT;
      const us4 o = { f2bf(r0), f2bf(r1), f2bf(r2), f2bf(r3) };
      *(us4*)&dst[((size_t)b*L_ + l)*512 + oin] = o;   // [l][c], 8B store
    }
  }
}

// ---------------------------------------------------------------------------
// MFMA attention v13 (round-6 verified best: 43.8us, FETCH 12.3MB):
// full-j single-pass, combine-free, i-tile 128, 8 waves, dbuf K/V staging
// with explicit drain, in-register P fragments (j-permuted vN), XCD-clustered
// block decode.
// ---------------------------------------------------------------------------
#define OPX 68  // epilogue bounce pitch

__global__ __launch_bounds__(512,4) void attn_v13(
    const unsigned short* __restrict__ qT, const unsigned short* __restrict__ kT,
    const unsigned short* __restrict__ vN,
    unsigned short* __restrict__ attnT)
{
  __shared__ unsigned short smem[16384];   // 32KB: buf b: K @ b*8192, V @ b*8192+4096
  const int t  = threadIdx.x;
  // ---- XCD-clustered decode
  const int id  = blockIdx.x;
  const int xcd = id & 7, s = id >> 3;
  const int pr  = xcd*4 + (s & 3);         // pair 0..31
  const int i0  = (s >> 2) * 128;          // i-tile 0..15
  const int h   = pr & 7, b = pr >> 3;
  const int lane = t&63, w = t>>6, n = lane&15, q4 = lane>>4;

  const unsigned short* kb0 = kT + (size_t)b*L_*512 + h*64;
  const unsigned short* vb  = vN + ((size_t)b*512 + h*64)*L_;

  // ---- Q B-fragments for this wave's 16 i-rows (col i = n)
  short8 qf[2];
#pragma unroll
  for (int kk=0; kk<2; kk++)
    qf[kk] = *(const short8*)(qT + ((size_t)b*L_ + i0 + w*16 + n)*512
                                 + h*64 + kk*32 + q4*8);

  // ---- all-ones bf16 B-fragment for the denominator MFMA
  short8 ones;
#pragma unroll
  for (int i=0;i<8;i++) ones[i] = (short)0x3F80;

  f32x4 oacc[4];
  f32x4 oden = (f32x4){0.f,0.f,0.f,0.f};
#pragma unroll
  for (int dt=0;dt<4;dt++) oacc[dt]=(f32x4){0.f,0.f,0.f,0.f};

  const float LIM = 14.4269504089f;          // 10*log2(e)

  // ---- prologue: stage tile 0 into buf0 (512 threads = 512 chunks each)
  {
    const int ch = t, row = ch>>3, lc = (ch&7)^(row&7);
    gl16(kb0 + (size_t)row*512 + lc*8, &smem[ch*8]);
    gl16(vb  + (size_t)row*L_ + lc*8,  &smem[4096 + ch*8]);
  }
  drain_dma();
  __syncthreads();                           // tile 0 landed (all waves)

  for (int j0=0; j0<L_; j0+=64){
    const int cur = (j0>>6)&1;
    const unsigned short* sk = &smem[cur*8192];
    const unsigned short* sv = &smem[cur*8192 + 4096];

    // ---- issue next tile's DMA into the other buffer (flight hides under
    //      this tile's MFMAs; drained explicitly before the loop barrier)
    if (j0+64 < L_){
      const int nb = cur^1;
      const int ch = t, row = ch>>3, lc = (ch&7)^(row&7);
      gl16(kb0 + (size_t)(j0+64+row)*512 + lc*8, &smem[nb*8192 + ch*8]);
      gl16(vb  + (size_t)row*L_ + j0+64 + lc*8,  &smem[nb*8192+4096 + ch*8]);
    }

    // ---- S^T = K*Q^T : D[j][i]; lane col = i (n), rows j = q4*4+r (+jt*16)
    f32x4 sacc[4];   // [jt]
#pragma unroll
    for (int jt=0;jt<4;jt++) sacc[jt]=(f32x4){0.f,0.f,0.f,0.f};
#pragma unroll
    for (int kk=0;kk<2;kk++){
      const int pc = ((kk*4+q4) ^ (n&7))*8;
      short8 aK[4];
#pragma unroll
      for (int jt=0;jt<4;jt++) aK[jt] = *(const short8*)&sk[(jt*16+n)*64 + pc];
#pragma unroll
      for (int jt=0;jt<4;jt++)
        sacc[jt] = __builtin_amdgcn_mfma_f32_16x16x32_bf16(aK[jt], qf[kk], sacc[jt], 0,0,0);
    }

    // ---- p = exp2(clamp(s)); trunc-pack pairs -> u32 words, kept in regs
    unsigned pw[4][2];
#pragma unroll
    for (int jt=0;jt<4;jt++){
      const float e0 = __builtin_amdgcn_exp2f(__builtin_amdgcn_fmed3f(sacc[jt][0],-LIM,LIM));
      const float e1 = __builtin_amdgcn_exp2f(__builtin_amdgcn_fmed3f(sacc[jt][1],-LIM,LIM));
      const float e2 = __builtin_amdgcn_exp2f(__builtin_amdgcn_fmed3f(sacc[jt][2],-LIM,LIM));
      const float e3 = __builtin_amdgcn_exp2f(__builtin_amdgcn_fmed3f(sacc[jt][3],-LIM,LIM));
      pw[jt][0] = pk_tr(e0,e1);
      pw[jt][1] = pk_tr(e2,e3);
    }

    // ---- O += P*V^T ; den += P*1. A-fragment built IN-REGISTER:
    // pA[kk] = {pw[kk][0], pw[kk][1], pw[kk+2][0], pw[kk+2][1]} holds
    // j = 16kk+4*q4+{0..3} and +32, matching the j-permuted s_v positions.
#pragma unroll
    for (int kk=0;kk<2;kk++){
      const int pcv = ((kk*4+q4) ^ (n&7))*8;
      short8 bV[4];
#pragma unroll
      for (int dt=0;dt<4;dt++) bV[dt] = *(const short8*)&sv[(dt*16+n)*64 + pcv];
      const short8 pA = mk8(pw[kk][0], pw[kk][1], pw[kk+2][0], pw[kk+2][1]);
#pragma unroll
      for (int dt=0;dt<4;dt++)
        oacc[dt] = __builtin_amdgcn_mfma_f32_16x16x32_bf16(pA, bV[dt], oacc[dt], 0,0,0);
      oden = __builtin_amdgcn_mfma_f32_16x16x32_bf16(pA, ones, oden, 0,0,0);
    }
    drain_dma();       // prefetch landed (explicit — do not trust barrier)
    __syncthreads();   // all waves done reading cur + all DMA drained
  }

  // ---- softmax divide in-register: oden[r] = den for row i = q4*4+r
  float inv[4];
#pragma unroll
  for (int r=0;r<4;r++) inv[r] = 1.0f/oden[r];

  // ---- epilogue: bounce O through the dead staging LDS (wave-private rows;
  // safe: last loop barrier already passed), then fully-coalesced 8B stores.
  unsigned short* sb = smem;   // 128 rows x OPX = 8704 us, fits in 16384
#pragma unroll
  for (int dt=0;dt<4;dt++)
#pragma unroll
    for (int r=0;r<4;r++)
      sb[(w*16 + q4*4 + r)*OPX + dt*16 + n] = f2bf(oacc[dt][r]*inv[r]);
#pragma unroll
  for (int it=0; it<4; it++){
    const int chunk = it*64 + lane;          // 256 us4 chunks for this wave
    const int row = chunk>>4, c4 = (chunk&15)*4;
    const us4 ov = *(const us4*)&sb[(w*16 + row)*OPX + c4];
    *(us4*)&attnT[((size_t)b*L_ + i0 + w*16 + row)*512 + h*64 + c4] = ov;
  }
}

// ---------------------------------------------------------------------------
// GroupNorm apply from bf16 y: stats from mfma_gemm<1>'s fused atomics.
// 512 blocks, quarter-group each; us8 bf16 loads, float4 fp32 stores.
// ---------------------------------------------------------------------------
__global__ __launch_bounds__(256) void gn_apply(
    const unsigned short* __restrict__ yb, const float* __restrict__ part,
    const float* __restrict__ gamma, const float* __restrict__ beta,
    float* __restrict__ out)
{
  const int blk = blockIdx.x;
  const int b = blk>>7, g = (blk>>2)&31, s = blk&3;
  const float sum = part[(b*32+g)*2+0];
  const float sq  = part[(b*32+g)*2+1];
  const float mu = sum*(1.0f/32768.0f);
  const float rs = rsqrtf(sq*(1.0f/32768.0f) - mu*mu + 1e-5f);
  const size_t base = ((size_t)b*C_ + g*16)*L_ + s*512;
  const int t = threadIdx.x;
#pragma unroll
  for (int i=0;i<4;i++){
    const int chunk = i*256 + t;            // 1024 chunks of 8 bf16
    const int row = chunk>>6;               // channel within group
    const int lc  = (chunk&63)*8;
    const int c = g*16 + row;
    const float ga = gamma[c]*rs, be = beta[c] - mu*ga;
    const size_t off = base + (size_t)row*L_ + lc;
    const short8 v = *(const short8*)(yb + off);
    float4 r1, r2;
    r1.x = bf2f((unsigned short)v[0])*ga + be;
    r1.y = bf2f((unsigned short)v[1])*ga + be;
    r1.z = bf2f((unsigned short)v[2])*ga + be;
    r1.w = bf2f((unsigned short)v[3])*ga + be;
    r2.x = bf2f((unsigned short)v[4])*ga + be;
    r2.y = bf2f((unsigned short)v[5])*ga + be;
    r2.z = bf2f((unsigned short)v[6])*ga + be;
    r2.w = bf2f((unsigned short)v[7])*ga + be;
    *(float4*)(out+off)   = r1;
    *(float4*)(out+off+4) = r2;
  }
}

// ---------------------------------------------------------------------------
extern "C" void kernel_launch(void* const* d_in, const int* in_sizes, int n_in,
                              void* d_out, int out_size, void* d_ws, size_t ws_size,
                              hipStream_t stream)
{
  (void)in_sizes; (void)n_in; (void)out_size; (void)ws_size;
  const float* x     = (const float*)d_in[0];
  const float* Wqkv  = (const float*)d_in[1];
  const float* bqkv  = (const float*)d_in[2];
  const float* Wproj = (const float*)d_in[3];
  const float* bproj = (const float*)d_in[4];
  const float* gamma = (const float*)d_in[5];
  const float* beta  = (const float*)d_in[6];
  float* out = (float*)d_out;
  char* ws = (char*)d_ws;

  const size_t MB = 1024*1024;
  unsigned short* qT    = (unsigned short*)(ws);            //  8 MB [b][l][512] (pre-scaled)
  unsigned short* kT    = (unsigned short*)(ws +  8*MB);    //  8 MB [b][l][512]
  unsigned short* vN    = (unsigned short*)(ws + 16*MB);    //  8 MB [b][512][l] (j-permuted)
  unsigned short* attnT = (unsigned short*)(ws + 24*MB);    //  8 MB [b][l][512]
  unsigned short* xT    = (unsigned short*)(ws + 32*MB);    //  8 MB; dead after QKV gemm
  unsigned short* Wqb   = (unsigned short*)(ws + 42*MB);    // 1.5 MB
  unsigned short* Wpb   = (unsigned short*)(ws + 44*MB);    // 0.5 MB
  unsigned short* yb    = (unsigned short*)(ws + 45*MB);    //  8 MB bf16 [b][512][l]
  float*          part  = (float*)        (ws + 61*MB);     // 1 KB (256 floats)

  prep_k      <<<dim3(5121),   256,0,stream>>>(x, Wqkv, Wproj, xT, Wqb, Wpb, part);
  mfma_gemm<0><<<dim3(16,12,4),256,0,stream>>>(Wqb, xT,    bqkv , nullptr, qT,kT,vN, nullptr);
  attn_v13    <<<dim3(512),    512,0,stream>>>(qT, kT, vN, attnT);
  mfma_gemm<1><<<dim3(16, 4,4),256,0,stream>>>(Wpb, attnT, bproj, x, nullptr,nullptr, yb, part);
  gn_apply    <<<dim3(512),    256,0,stream>>>(yb, part, gamma, beta, out);
}

// Round 11
// 174.670 us; speedup vs baseline: 1.4300x; 1.0049x over previous
//
#include <hip/hip_runtime.h>
#include <cstddef>

#define B_ 4
#define C_ 512
#define L_ 2048

typedef __attribute__((ext_vector_type(8))) short  short8;   // 8 bf16 (4 VGPRs)
typedef __attribute__((ext_vector_type(4))) float  f32x4;
typedef __attribute__((ext_vector_type(4))) unsigned short us4;

#define AS1 __attribute__((address_space(1)))
#define AS3 __attribute__((address_space(3)))

__device__ __forceinline__ float clip10(float v){ return fminf(fmaxf(v,-10.0f),10.0f); }

// round-to-nearest-even fp32 -> bf16 (finite inputs only; ours are clipped)
__device__ __forceinline__ unsigned short f2bf(float f){
  union { float f; unsigned u; } v; v.f = f;
  unsigned r = v.u + 0x7fffu + ((v.u >> 16) & 1u);
  return (unsigned short)(r >> 16);
}
// truncation-pack two fp32 -> bf16x2 in ONE v_perm_b32 (lo -> low half)
__device__ __forceinline__ unsigned pk_tr(float lo, float hi){
  return __builtin_amdgcn_perm(__float_as_uint(hi), __float_as_uint(lo), 0x07060302u);
}
__device__ __forceinline__ float bf2f(unsigned short u){
  return __uint_as_float(((unsigned)u)<<16);
}
// async 16B global -> LDS (direct-to-shared DMA)
__device__ __forceinline__ void gl16(const void* g, void* l){
  __builtin_amdgcn_global_load_lds((const AS1 unsigned*)g, (AS3 unsigned*)l, 16, 0, 0);
}
// explicit LDS-DMA drain: do NOT rely on compiler inserting vmcnt(0) at the
// barrier when the DMA issue is far from it.
__device__ __forceinline__ void drain_dma(){
  asm volatile("s_waitcnt vmcnt(0)" ::: "memory");
}
// assemble 4 packed-bf16 u32 words into one MFMA A/B fragment
__device__ __forceinline__ short8 mk8(unsigned a, unsigned b, unsigned c, unsigned d){
  union { unsigned u[4]; short8 s; } v;
  v.u[0]=a; v.u[1]=b; v.u[2]=c; v.u[3]=d;
  return v.s;
}

// ---------------------------------------------------------------------------
// Prep: blocks 0..4095 transpose x -> xT bf16; 4096..5119 convert W;
// block 5120 zeroes the groupnorm partial accumulators (re-poison-safe).
// ---------------------------------------------------------------------------
__global__ __launch_bounds__(256) void prep_k(
    const float* __restrict__ x, const float* __restrict__ Wq,
    const float* __restrict__ Wp, unsigned short* __restrict__ xT,
    unsigned short* __restrict__ Wqb, unsigned short* __restrict__ Wpb,
    float* __restrict__ part)
{
  const int blk = blockIdx.x;
  const int t = threadIdx.x;
  if (blk < 4096){
    __shared__ float tile[32][33];
    const int b = blk>>10, rem = blk&1023;
    const int c0 = (rem>>6)*32, l0 = (rem&63)*32;
    const int cr = t>>3, lc = (t&7)*4;
    const float4 v = *(const float4*)(x + ((size_t)b*C_ + c0+cr)*L_ + l0 + lc);
    tile[cr][lc]=v.x; tile[cr][lc+1]=v.y; tile[cr][lc+2]=v.z; tile[cr][lc+3]=v.w;
    __syncthreads();
    const int lr = t>>3, cc = (t&7)*4;
    const us4 o = { f2bf(tile[cc][lr]), f2bf(tile[cc+1][lr]),
                    f2bf(tile[cc+2][lr]), f2bf(tile[cc+3][lr]) };
    *(us4*)(xT + ((size_t)b*L_ + l0+lr)*C_ + c0 + cc) = o;
  } else if (blk < 5120){
    const int i = (blk-4096)*256 + t;       // float4 index
    const int NQ = 1536*512/4;
    const float* src; unsigned short* dst; int j;
    if (i < NQ){ src = Wq; dst = Wqb; j = i; }
    else       { src = Wp; dst = Wpb; j = i - NQ; }
    const float4 v = *(const float4*)(src + (size_t)j*4);
    const us4 o = { f2bf(v.x), f2bf(v.y), f2bf(v.z), f2bf(v.w) };
    *(us4*)(dst + (size_t)j*4) = o;
  } else {
    part[t] = 0.f;                          // 4 batches x 32 groups x {sum,sq}
  }
}

// ---------------------------------------------------------------------------
// bf16 MFMA GEMM (LDS-DMA), 128x128 tile, BK=64, K=512. (round-2 verified)
// LDS chunks XOR-swizzled: physical chunk = logical ^ (row&7).
// MODE 0 (QKV): +bias, clip; q scaled by 0.125*log2e; q/k bf16 [b][l][512];
//               v bf16 [b][512][l] with l J-PERMUTED inside each 64-block
//               so the attention PV A-fragment assembles in-register.
// MODE 1 (proj): SWAPPED operands (D^T): lane owns 4 CONSECUTIVE l of one
//               channel -> float4 x-load, us4 bf16 y-store (coalesced, half
//               traffic). Stats fp32 BEFORE rounding; wave-reduced, atomic.
// ---------------------------------------------------------------------------
template<int MODE>
__global__ __launch_bounds__(256) void mfma_gemm(
    const unsigned short* __restrict__ Wb, const unsigned short* __restrict__ Bin,
    const float* __restrict__ bias, const float* __restrict__ xres,
    unsigned short* __restrict__ qT, unsigned short* __restrict__ kT,
    unsigned short* __restrict__ vN,      // MODE1: yb bf16 [b][512][l]
    float* __restrict__ part)
{
  __shared__ unsigned short SA[128*64];   // [m][k'] bf16, 16KB
  __shared__ unsigned short SB[128*64];   // [n][k'] bf16, 16KB
  const int t = threadIdx.x;
  const int b = blockIdx.z;
  const int mb = blockIdx.y, n0 = blockIdx.x*128, m0 = mb*128;
  const int lane = t&63, w = t>>6, wm = w>>1, wn = w&1;
  const int n = lane&15, q4 = lane>>4;
  const bool SWAP = (MODE==1) || (MODE==0 && mb>=8);

  f32x4 acc[4][4];
#pragma unroll
  for (int i=0;i<4;i++)
#pragma unroll
    for (int j=0;j<4;j++) acc[i][j] = (f32x4){0.f,0.f,0.f,0.f};

  const unsigned short* Arow = Wb + (size_t)m0*512;
  const unsigned short* Brow = Bin + ((size_t)b*L_ + n0)*512;

  for (int kt=0; kt<8; kt++){
    const int k0 = kt*64;
    __syncthreads();                     // prev-iter fragment reads done
#pragma unroll
    for (int i=0;i<4;i++){
      const int ch = t + 256*i;          // 0..1023 : row=ch>>3, phys chunk=ch&7
      const int row = ch>>3, lc = (ch&7) ^ (row&7);
      gl16(Arow + (size_t)row*512 + k0 + lc*8, &SA[ch*8]);
      gl16(Brow + (size_t)row*512 + k0 + lc*8, &SB[ch*8]);
    }
    drain_dma();
    __syncthreads();                     // all DMA landed
#pragma unroll
    for (int kk=0;kk<2;kk++){
      short8 aF[4], bF[4];
      const int pc = ((kk*4+q4) ^ (n&7))*8;
#pragma unroll
      for (int mt=0;mt<4;mt++) aF[mt] = *(const short8*)&SA[(wm*64+mt*16+n)*64 + pc];
#pragma unroll
      for (int nt=0;nt<4;nt++) bF[nt] = *(const short8*)&SB[(wn*64+nt*16+n)*64 + pc];
      if (SWAP){
#pragma unroll
        for (int mt=0;mt<4;mt++)
#pragma unroll
          for (int nt=0;nt<4;nt++)
            acc[mt][nt] = __builtin_amdgcn_mfma_f32_16x16x32_bf16(bF[nt], aF[mt], acc[mt][nt], 0,0,0);
      } else {
#pragma unroll
        for (int mt=0;mt<4;mt++)
#pragma unroll
          for (int nt=0;nt<4;nt++)
            acc[mt][nt] = __builtin_amdgcn_mfma_f32_16x16x32_bf16(aF[mt], bF[nt], acc[mt][nt], 0,0,0);
      }
    }
  }

  const float QS = 0.180336880f;   // 0.125 * log2(e), folded into q
  if (MODE==0 && SWAP){
    // D^T: acc[mt][nt][r] = (l = n0+wn*64+nt*16+q4*4+r, c = m0+wm*64+mt*16+n)
    // store at J-PERMUTED l within the 64-block: u=nt*16+q4*4+r ->
    //   p = r + (nt>>1)*4 + (q4&1)*8 + (q4>>1)*16 + (nt&1)*32
#pragma unroll
    for (int mt=0;mt<4;mt++){
      const int o = m0 + wm*64 + mt*16 + n;
      const float bv = bias[o];
#pragma unroll
      for (int nt=0;nt<4;nt++){
        const int p = ((nt>>1)<<2) | ((q4&1)<<3) | ((q4>>1)<<4) | ((nt&1)<<5);
        const int l = n0 + wn*64 + p;
        const float r0=clip10(acc[mt][nt][0]+bv), r1=clip10(acc[mt][nt][1]+bv),
                    r2=clip10(acc[mt][nt][2]+bv), r3=clip10(acc[mt][nt][3]+bv);
        const us4 ov = { f2bf(r0), f2bf(r1), f2bf(r2), f2bf(r3) };
        *(us4*)&vN[((size_t)b*512 + (o-1024))*L_ + l] = ov;   // 8B store along l
      }
    }
    return;
  }
  if (MODE==1){
    // D^T, NO permutation: acc[mt][nt][r] = y at (c = m0+wm*64+mt*16+n,
    // l = n0+wn*64+nt*16+q4*4+r). One float4 x-load + one us4 y-store per nt.
#pragma unroll
    for (int mt=0;mt<4;mt++){
      const int o = m0 + wm*64 + mt*16 + n;
      const float bv = bias[o];
      float gs=0.f, gq=0.f;
#pragma unroll
      for (int nt=0;nt<4;nt++){
        const int l = n0 + wn*64 + nt*16 + q4*4;
        const float4 xv = *(const float4*)(xres + ((size_t)b*512 + o)*L_ + l);
        const float y0=acc[mt][nt][0]+bv+xv.x, y1=acc[mt][nt][1]+bv+xv.y,
                    y2=acc[mt][nt][2]+bv+xv.z, y3=acc[mt][nt][3]+bv+xv.w;
        gs += (y0+y1)+(y2+y3);
        gq += (y0*y0+y1*y1)+(y2*y2+y3*y3);
        const us4 ov = { f2bf(y0), f2bf(y1), f2bf(y2), f2bf(y3) };
        *(us4*)&vN[((size_t)b*512 + o)*L_ + l] = ov;          // yb, 8B along l
      }
      // wave covers exactly one 16-channel group for this mt
#pragma unroll
      for (int off=1; off<64; off<<=1){
        gs += __shfl_xor(gs, off);
        gq += __shfl_xor(gq, off);
      }
      if (lane==0){
        const int g = mb*8 + wm*4 + mt;
        atomicAdd(&part[(b*32+g)*2+0], gs);
        atomicAdd(&part[(b*32+g)*2+1], gq);
      }
    }
    return;
  }
  // ---- MODE0 q/k epilogue: C row = m (quad*4+reg), col = n (lane&15)
#pragma unroll
  for (int mt=0;mt<4;mt++){
    const int obase = m0 + wm*64 + mt*16 + q4*4;
    const float b0=bias[obase], b1=bias[obase+1], b2=bias[obase+2], b3=bias[obase+3];
#pragma unroll
    for (int nt=0;nt<4;nt++){
      const int l = n0 + wn*64 + nt*16 + n;
      float r0=clip10(acc[mt][nt][0]+b0), r1=clip10(acc[mt][nt][1]+b1),
            r2=clip10(acc[mt][nt][2]+b2), r3=clip10(acc[mt][nt][3]+b3);
      const int typ = mb>>2;                     // 0=q 1=k (v handled above)
      const int oin = obase - typ*512;
      if (typ==0){ r0*=QS; r1*=QS; r2*=QS; r3*=QS; }
      unsigned short* dst = (typ==0) ? qT : kT;
      const us4 o = { f2bf(r0), f2bf(r1), f2bf(r2), f2bf(r3) };
      *(us4*)&dst[((size_t)b*L_ + l)*512 + oin] = o;   // [l][c], 8B store
    }
  }
}

// ---------------------------------------------------------------------------
// MFMA attention v15 = v13 + wave-level j-split for FULL occupancy.
// v13 (2 blocks/CU x 8 waves = 16 waves/CU, Occupancy 31%) was issue/latency
// bound with MfmaUtil 33%. v15: 1024-thread blocks, 16 waves; wave w owns
// i-rows (w&7)*16 and j-half (w>>3). Each 8-wave group runs the EXACT v13
// pipeline over its 16 j-tiles with its own 32KB K/V dbuf (64KB total ->
// still 2 blocks/CU = 32 waves/CU = 100%). End: group 1 parks fp32 O/den
// partials in the dead staging LDS (pitch-21 to dodge bank conflicts), one
// barrier, group 0 adds lane-matched partials, divides, stores via the
// existing coalesced bounce. No global combine traffic; fp32-exact.
// ---------------------------------------------------------------------------
#define OPX 68   // epilogue bounce pitch (us)
#define PPITCH 21  // partial-exchange pitch (floats; gcd(21,32)=1)

__global__ __launch_bounds__(1024,8) void attn_v15(
    const unsigned short* __restrict__ qT, const unsigned short* __restrict__ kT,
    const unsigned short* __restrict__ vN,
    unsigned short* __restrict__ attnT)
{
  __shared__ unsigned short smem[32768];   // 64KB: group g @ g*16384: cur*8192 + {K:0,V:4096}
  const int t  = threadIdx.x;
  // ---- XCD-clustered decode (verified r6: FETCH 69.7->12.3MB)
  const int id  = blockIdx.x;
  const int xcd = id & 7, s = id >> 3;
  const int pr  = xcd*4 + (s & 3);         // pair 0..31
  const int i0  = (s >> 2) * 128;          // i-tile 0..15
  const int h   = pr & 7, b = pr >> 3;
  const int lane = t&63, w = t>>6, n = lane&15, q4 = lane>>4;
  const int iw = w & 7;                    // i-row band 0..7
  const int jg = w >> 3;                   // j-half 0..1
  const int jbase = jg*1024;

  const unsigned short* kb0 = kT + (size_t)b*L_*512 + h*64;
  const unsigned short* vb  = vN + ((size_t)b*512 + h*64)*L_;

  // ---- Q B-fragments for this wave's 16 i-rows (col i = n)
  short8 qf[2];
#pragma unroll
  for (int kk=0; kk<2; kk++)
    qf[kk] = *(const short8*)(qT + ((size_t)b*L_ + i0 + iw*16 + n)*512
                                 + h*64 + kk*32 + q4*8);

  // ---- all-ones bf16 B-fragment for the denominator MFMA
  short8 ones;
#pragma unroll
  for (int i=0;i<8;i++) ones[i] = (short)0x3F80;

  f32x4 oacc[4];
  f32x4 oden = (f32x4){0.f,0.f,0.f,0.f};
#pragma unroll
  for (int dt=0;dt<4;dt++) oacc[dt]=(f32x4){0.f,0.f,0.f,0.f};

  const float LIM = 14.4269504089f;          // 10*log2(e)

  // ---- staging: each group's 512 threads stage their own j-half tile
  const int tg = t & 511;                    // thread-in-group (t>>9 == jg)
  const int srow = tg>>3, slc = (tg&7)^(srow&7);
  unsigned short* gbase = &smem[jg*16384];

  // ---- prologue: stage tile 0 of own j-half into buf0
  gl16(kb0 + (size_t)(jbase+srow)*512 + slc*8, &gbase[tg*8]);
  gl16(vb  + (size_t)srow*L_ + jbase  + slc*8, &gbase[4096 + tg*8]);
  drain_dma();
  __syncthreads();                           // tile 0 landed (all waves)

  for (int jt=0; jt<16; jt++){
    const int cur = jt&1;
    const unsigned short* sk = &gbase[cur*8192];
    const unsigned short* sv = &gbase[cur*8192 + 4096];

    // ---- issue next tile's DMA into the other buffer (flight hides under
    //      this tile's MFMAs; drained explicitly before the loop barrier)
    if (jt < 15){
      unsigned short* nb = &gbase[(cur^1)*8192];
      const int jn = jbase + (jt+1)*64;
      gl16(kb0 + (size_t)(jn+srow)*512 + slc*8, &nb[tg*8]);
      gl16(vb  + (size_t)srow*L_ + jn  + slc*8, &nb[4096 + tg*8]);
    }

    // ---- S^T = K*Q^T : D[j][i]; lane col = i (n), rows j = q4*4+r (+jt*16)
    f32x4 sacc[4];   // [jt16]
#pragma unroll
    for (int j4=0;j4<4;j4++) sacc[j4]=(f32x4){0.f,0.f,0.f,0.f};
#pragma unroll
    for (int kk=0;kk<2;kk++){
      const int pc = ((kk*4+q4) ^ (n&7))*8;
      short8 aK[4];
#pragma unroll
      for (int j4=0;j4<4;j4++) aK[j4] = *(const short8*)&sk[(j4*16+n)*64 + pc];
#pragma unroll
      for (int j4=0;j4<4;j4++)
        sacc[j4] = __builtin_amdgcn_mfma_f32_16x16x32_bf16(aK[j4], qf[kk], sacc[j4], 0,0,0);
    }

    // ---- p = exp2(clamp(s)); trunc-pack pairs -> u32 words, kept in regs
    unsigned pw[4][2];
#pragma unroll
    for (int j4=0;j4<4;j4++){
      const float e0 = __builtin_amdgcn_exp2f(__builtin_amdgcn_fmed3f(sacc[j4][0],-LIM,LIM));
      const float e1 = __builtin_amdgcn_exp2f(__builtin_amdgcn_fmed3f(sacc[j4][1],-LIM,LIM));
      const float e2 = __builtin_amdgcn_exp2f(__builtin_amdgcn_fmed3f(sacc[j4][2],-LIM,LIM));
      const float e3 = __builtin_amdgcn_exp2f(__builtin_amdgcn_fmed3f(sacc[j4][3],-LIM,LIM));
      pw[j4][0] = pk_tr(e0,e1);
      pw[j4][1] = pk_tr(e2,e3);
    }

    // ---- O += P*V^T ; den += P*1. A-fragment built IN-REGISTER:
    // pA[kk] = {pw[kk][0], pw[kk][1], pw[kk+2][0], pw[kk+2][1]} holds
    // j = 16kk+4*q4+{0..3} and +32, matching the j-permuted s_v positions.
#pragma unroll
    for (int kk=0;kk<2;kk++){
      const int pcv = ((kk*4+q4) ^ (n&7))*8;
      short8 bV[4];
#pragma unroll
      for (int dt=0;dt<4;dt++) bV[dt] = *(const short8*)&sv[(dt*16+n)*64 + pcv];
      const short8 pA = mk8(pw[kk][0], pw[kk][1], pw[kk+2][0], pw[kk+2][1]);
#pragma unroll
      for (int dt=0;dt<4;dt++)
        oacc[dt] = __builtin_amdgcn_mfma_f32_16x16x32_bf16(pA, bV[dt], oacc[dt], 0,0,0);
      oden = __builtin_amdgcn_mfma_f32_16x16x32_bf16(pA, ones, oden, 0,0,0);
    }
    drain_dma();       // prefetch landed (explicit — do not trust barrier)
    __syncthreads();   // all waves done reading cur + all DMA drained
  }

  // ---- combine: group 1 parks fp32 partials in dead staging LDS
  float* pbuf = (float*)smem;          // 8*64*21 floats = 43008 B
  if (jg == 1){
    const int slot = (iw*64 + lane)*PPITCH;
#pragma unroll
    for (int dt=0;dt<4;dt++)
#pragma unroll
      for (int r=0;r<4;r++) pbuf[slot + dt*4 + r] = oacc[dt][r];
#pragma unroll
    for (int r=0;r<4;r++) pbuf[slot + 16 + r] = oden[r];
  }
  __syncthreads();
  if (jg == 1) return;                 // group 1 done (after barrier)

  {
    const int slot = (iw*64 + lane)*PPITCH;
#pragma unroll
    for (int dt=0;dt<4;dt++)
#pragma unroll
      for (int r=0;r<4;r++) oacc[dt][r] += pbuf[slot + dt*4 + r];
#pragma unroll
    for (int r=0;r<4;r++) oden[r] += pbuf[slot + 16 + r];
  }

  // ---- softmax divide in-register: oden[r] = den for row i = q4*4+r
  float inv[4];
#pragma unroll
  for (int r=0;r<4;r++) inv[r] = 1.0f/oden[r];

  // ---- epilogue: bounce O through LDS after pbuf region (no overlap),
  // wave-private rows, then fully-coalesced 8B stores.
  unsigned short* sb = &smem[21504];   // 128 rows x OPX = 8704 us; 21504+8704 <= 32768
#pragma unroll
  for (int dt=0;dt<4;dt++)
#pragma unroll
    for (int r=0;r<4;r++)
      sb[(iw*16 + q4*4 + r)*OPX + dt*16 + n] = f2bf(oacc[dt][r]*inv[r]);
#pragma unroll
  for (int it=0; it<4; it++){
    const int chunk = it*64 + lane;          // 256 us4 chunks for this wave
    const int row = chunk>>4, c4 = (chunk&15)*4;
    const us4 ov = *(const us4*)&sb[(iw*16 + row)*OPX + c4];
    *(us4*)&attnT[((size_t)b*L_ + i0 + iw*16 + row)*512 + h*64 + c4] = ov;
  }
}

// ---------------------------------------------------------------------------
// GroupNorm apply from bf16 y: stats from mfma_gemm<1>'s fused atomics.
// 512 blocks, quarter-group each; short8 bf16 loads, float4 fp32 stores.
// ---------------------------------------------------------------------------
__global__ __launch_bounds__(256) void gn_apply(
    const unsigned short* __restrict__ yb, const float* __restrict__ part,
    const float* __restrict__ gamma, const float* __restrict__ beta,
    float* __restrict__ out)
{
  const int blk = blockIdx.x;
  const int b = blk>>7, g = (blk>>2)&31, s = blk&3;
  const float sum = part[(b*32+g)*2+0];
  const float sq  = part[(b*32+g)*2+1];
  const float mu = sum*(1.0f/32768.0f);
  const float rs = rsqrtf(sq*(1.0f/32768.0f) - mu*mu + 1e-5f);
  const size_t base = ((size_t)b*C_ + g*16)*L_ + s*512;
  const int t = threadIdx.x;
#pragma unroll
  for (int i=0;i<4;i++){
    const int chunk = i*256 + t;            // 1024 chunks of 8 bf16
    const int row = chunk>>6;               // channel within group
    const int lc  = (chunk&63)*8;
    const int c = g*16 + row;
    const float ga = gamma[c]*rs, be = beta[c] - mu*ga;
    const size_t off = base + (size_t)row*L_ + lc;
    const short8 v = *(const short8*)(yb + off);
    float4 r1, r2;
    r1.x = bf2f((unsigned short)v[0])*ga + be;
    r1.y = bf2f((unsigned short)v[1])*ga + be;
    r1.z = bf2f((unsigned short)v[2])*ga + be;
    r1.w = bf2f((unsigned short)v[3])*ga + be;
    r2.x = bf2f((unsigned short)v[4])*ga + be;
    r2.y = bf2f((unsigned short)v[5])*ga + be;
    r2.z = bf2f((unsigned short)v[6])*ga + be;
    r2.w = bf2f((unsigned short)v[7])*ga + be;
    *(float4*)(out+off)   = r1;
    *(float4*)(out+off+4) = r2;
  }
}

// ---------------------------------------------------------------------------
extern "C" void kernel_launch(void* const* d_in, const int* in_sizes, int n_in,
                              void* d_out, int out_size, void* d_ws, size_t ws_size,
                              hipStream_t stream)
{
  (void)in_sizes; (void)n_in; (void)out_size; (void)ws_size;
  const float* x     = (const float*)d_in[0];
  const float* Wqkv  = (const float*)d_in[1];
  const float* bqkv  = (const float*)d_in[2];
  const float* Wproj = (const float*)d_in[3];
  const float* bproj = (const float*)d_in[4];
  const float* gamma = (const float*)d_in[5];
  const float* beta  = (const float*)d_in[6];
  float* out = (float*)d_out;
  char* ws = (char*)d_ws;

  const size_t MB = 1024*1024;
  unsigned short* qT    = (unsigned short*)(ws);            //  8 MB [b][l][512] (pre-scaled)
  unsigned short* kT    = (unsigned short*)(ws +  8*MB);    //  8 MB [b][l][512]
  unsigned short* vN    = (unsigned short*)(ws + 16*MB);    //  8 MB [b][512][l] (j-permuted)
  unsigned short* attnT = (unsigned short*)(ws + 24*MB);    //  8 MB [b][l][512]
  unsigned short* xT    = (unsigned short*)(ws + 32*MB);    //  8 MB; dead after QKV gemm
  unsigned short* Wqb   = (unsigned short*)(ws + 42*MB);    // 1.5 MB
  unsigned short* Wpb   = (unsigned short*)(ws + 44*MB);    // 0.5 MB
  unsigned short* yb    = (unsigned short*)(ws + 45*MB);    //  8 MB bf16 [b][512][l]
  float*          part  = (float*)        (ws + 61*MB);     // 1 KB (256 floats)

  prep_k      <<<dim3(5121),   256,0,stream>>>(x, Wqkv, Wproj, xT, Wqb, Wpb, part);
  mfma_gemm<0><<<dim3(16,12,4),256,0,stream>>>(Wqb, xT,    bqkv , nullptr, qT,kT,vN, nullptr);
  attn_v15    <<<dim3(512),   1024,0,stream>>>(qT, kT, vN, attnT);
  mfma_gemm<1><<<dim3(16, 4,4),256,0,stream>>>(Wpb, attnT, bproj, x, nullptr,nullptr, yb, part);
  gn_apply    <<<dim3(512),    256,0,stream>>>(yb, part, gamma, beta, out);
}